// Round 14
// baseline (823.035 us; speedup 1.0000x reference)
//
#include <hip/hip_runtime.h>

#define NS 32   // n_state
#define NI 16   // n_input
#define NA 48   // n_all
#define TT 64   // horizon
#define HT 32   // half horizon
#define CSZ (NA * NA)      // 2304 floats per C_t

// f64 reciprocal: f32 rcp seed + 2 Newton steps (~1 ulp; GJ margin ~1000x)
__device__ __forceinline__ double fast_rcp(double x) {
    double r = (double)(1.0f / (float)x);
    r = r * (2.0 - x * r);
    r = r * (2.0 - x * r);
    return r;
}

// ---------------- FAST PATH ----------------
// 1024 threads (16 waves = 4/SIMD: latency hiding — round 12/13 ran 1 wave/SIMD
// and was TLP-starved). Single backward sweep (64 steps, 4 barriers each),
// K_t/P_t (f32) to d_ws; single-wave shfl forward; parallel mu pass.
// Numerics bit-compatible with passing rounds 9-13: f64 state, ascending-k
// dots, fused exact symmetrization (REQUIRED — unsymmetrized diverges,
// 126976 signature), register/__shfl GJ in wave 0, f32 out.
__launch_bounds__(1024, 1)
__global__ void lqr_fast(const float* __restrict__ Ag,
                         const float* __restrict__ Bg,
                         const float* __restrict__ Cg,
                         const float* __restrict__ x0g,
                         float* __restrict__ out,
                         float* __restrict__ Kall,   // [TT][NI][NS] f32
                         float* __restrict__ Pall)   // [TT][NS][NS] f32
{
    __shared__ float  sXT[TT][NS];      //  8192 B  x trajectory (f32)
    __shared__ double sA[NS][33];       //  8448 B  (odd strides: conflict-free)
    __shared__ double sB[NS][17];       //  4352 B
    __shared__ double sP[NS][33];       //  8448 B  Riccati state (f64)
    __shared__ double sPA[NS][33];      //  8448 B  P*A
    __shared__ double sPB[NS][17];      //  4352 B  P*B
    __shared__ double sHs[NI][33];      //  4224 B  S^T + B^T P A
    __shared__ double sKt[NI][33];      //  4224 B  K_t (f64)
    __shared__ double sGi[NI][17];      //  2176 B  G^{-1}
    __shared__ double sPp[NS][33];      //  8448 B  Q + A^T P A  (~60 KB)

    const int tid  = threadIdx.x;
    const int wid  = tid >> 6, lane = tid & 63;
    const int ei   = tid >> 5, ej = tid & 31;     // 32x32 one-elem roles

    for (int idx = tid; idx < NS * NS; idx += 1024) {
        sA[idx >> 5][idx & 31] = (double)Ag[idx];
        sP[idx >> 5][idx & 31] = 0.0;
    }
    for (int idx = tid; idx < NS * NI; idx += 1024)
        sB[idx >> 4][idx & 15] = (double)Bg[idx];
    __syncthreads();

    // ---- backward sweep: 64 steps, 4 barriers each ----
    for (int t = TT - 1; t >= 0; --t) {
        const float* Ct = Cg + t * CSZ;

        // phase 1: PA[ei][ej] (all 1024); PB for tid<512
        {
            double a = 0.0;
            for (int k = 0; k < NS; ++k) a += sP[ei][k] * sA[k][ej];
            sPA[ei][ej] = a;
            if (tid < 512) {
                const int bi = tid >> 4, bj = tid & 15;
                double b = 0.0;
                for (int k = 0; k < NS; ++k) b += sP[bi][k] * sB[k][bj];
                sPB[bi][bj] = b;
            }
        }
        __syncthreads();                                   // barrier A

        // phase 2 (overlapped): wave0 -> G^{-1} (register GJ via __shfl);
        //                       waves 1-15 (960 thr) -> Hs, Pp
        if (wid == 0) {
            const int ri = lane & 15, cg = lane >> 4, jb = cg * 4;
            double g0 = (double)Ct[(NS + ri) * NA + NS + jb + 0];
            double g1 = (double)Ct[(NS + ri) * NA + NS + jb + 1];
            double g2 = (double)Ct[(NS + ri) * NA + NS + jb + 2];
            double g3 = (double)Ct[(NS + ri) * NA + NS + jb + 3];
            for (int k = 0; k < NS; ++k) {
                const double b = sB[k][ri];
                g0 += b * sPB[k][jb + 0]; g1 += b * sPB[k][jb + 1];
                g2 += b * sPB[k][jb + 2]; g3 += b * sPB[k][jb + 3];
            }
#pragma unroll
            for (int k = 0; k < NI; ++k) {
                const double myslot = ((k & 3) == 0) ? g0 : ((k & 3) == 1) ? g1
                                     : ((k & 3) == 2) ? g2 : g3;
                const int    plv  = k + ((k >> 2) << 4);      // lane of (k,k)
                const double piv  = __shfl(myslot, plv, 64);
                const double cv   = __shfl(myslot, ri + ((k >> 2) << 4), 64); // (ri,k)
                const double pr0  = __shfl(g0, k + (cg << 4), 64);            // (k,jb+j)
                const double pr1  = __shfl(g1, k + (cg << 4), 64);
                const double pr2  = __shfl(g2, k + (cg << 4), 64);
                const double pr3  = __shfl(g3, k + (cg << 4), 64);
                const double ip   = fast_rcp(piv);
                const bool   rk   = (ri == k);
                g0 = rk ? ((jb + 0 == k) ? ip : pr0 * ip)
                        : ((jb + 0 == k) ? -cv * ip : g0 - cv * pr0 * ip);
                g1 = rk ? ((jb + 1 == k) ? ip : pr1 * ip)
                        : ((jb + 1 == k) ? -cv * ip : g1 - cv * pr1 * ip);
                g2 = rk ? ((jb + 2 == k) ? ip : pr2 * ip)
                        : ((jb + 2 == k) ? -cv * ip : g2 - cv * pr2 * ip);
                g3 = rk ? ((jb + 3 == k) ? ip : pr3 * ip)
                        : ((jb + 3 == k) ? -cv * ip : g3 - cv * pr3 * ip);
            }
            sGi[ri][jb + 0] = g0; sGi[ri][jb + 1] = g1;
            sGi[ri][jb + 2] = g2; sGi[ri][jb + 3] = g3;
        } else {
            const int e0 = tid - 64;
            for (int e = e0; e < NI * NS; e += 960) {
                const int i = e >> 5, j = e & 31;
                double acc = (double)Ct[j * NA + NS + i];
                for (int k = 0; k < NS; ++k) acc += sB[k][i] * sPA[k][j];
                sHs[i][j] = acc;
            }
            for (int e = e0; e < NS * NS; e += 960) {
                const int i = e >> 5, j = e & 31;
                double acc = (double)Ct[i * NA + j];
                for (int k = 0; k < NS; ++k) acc += sA[k][i] * sPA[k][j];
                sPp[i][j] = acc;
            }
        }
        __syncthreads();                                   // barrier B

        // phase 3: K = G^{-1} Hs  (512 elems, threads 0..511, chain 16)
        if (tid < 512) {
            const int i = tid >> 5, j = tid & 31;
            double a = 0.0;
            for (int k = 0; k < NI; ++k) a += sGi[i][k] * sHs[k][j];
            sKt[i][j] = a;
            Kall[t * NI * NS + i * NS + j] = (float)a;
        }
        __syncthreads();                                   // barrier C

        // phase 4: P[ei][ej] = 0.5*((Pp - Hs^T K)[ei][ej] + (..)[ej][ei])
        {
            double a = sPp[ei][ej], b = sPp[ej][ei];
            for (int k = 0; k < NI; ++k) {
                a -= sHs[k][ei] * sKt[k][ej];
                b -= sHs[k][ej] * sKt[k][ei];
            }
            const double r = 0.5 * (a + b);
            sP[ei][ej] = r;
            Pall[t * NS * NS + ei * NS + ej] = (float)r;
        }
        __syncthreads();                                   // barrier D
    }

    // ---- forward rollout: single wave, x in registers, shfl broadcast ----
    if (wid == 0) {
        const int row = lane & 31;
        double x = 0.0;
        if (lane < NS) x = (double)x0g[lane];
        for (int t = 0; t < TT; ++t) {
            if (lane < NS) {
                const float xv = (float)x;
                sXT[t][lane] = xv;
                out[t * NA + lane] = xv;
            }
            const float* Kt = Kall + t * NI * NS + (lane & 15) * NS;
            double accU = 0.0;
            for (int k = 0; k < NS; ++k) {
                const double xk = __shfl(x, k, 64);
                accU += (double)Kt[k] * xk;
            }
            const double u = -accU;
            if (lane < NI) out[t * NA + NS + lane] = (float)u;
            if (t < TT - 1) {
                double accX = 0.0;
                for (int k = 0; k < NS; ++k) {
                    const double xk = __shfl(x, k, 64);
                    accX += sA[row][k] * xk;
                }
                for (int k = 0; k < NI; ++k) {
                    const double uk = __shfl(u, k, 64);   // lane k holds u row k
                    accX += sB[row][k] * uk;
                }
                x = accX;
            }
        }
    }
    __syncthreads();

    // ---- mu pass: mu_t = P_t x_t (2048 parallel dots); mu_0 negated ----
    for (int e = tid; e < TT * NS; e += 1024) {
        const int t = e >> 5, i = e & 31;
        const float* Pt = Pall + t * NS * NS + i * NS;
        double acc = 0.0;
        for (int k = 0; k < NS; ++k) acc += (double)Pt[k] * (double)sXT[t][k];
        if (t == 0) acc = -acc;
        out[NA * TT + t * NS + i] = (float)acc;
    }
}

// ---------------- FALLBACK (round-11/12, passing) — if ws_size < 384 KB ----
__launch_bounds__(256, 1)
__global__ void lqr_kernel_fb(const float* __restrict__ Ag,
                              const float* __restrict__ Bg,
                              const float* __restrict__ Cg,
                              const float* __restrict__ x0g,
                              float* __restrict__ out)
{
    __shared__ float  sKh[HT][NI][NS];
    __shared__ float  sXT[TT][NS];
    __shared__ double sA[NS][NS];
    __shared__ double sB[NS][NI];
    __shared__ double sP[NS][NS];
    __shared__ double sPA[NS][NS];
    __shared__ double sPB[NS][NI];
    __shared__ double sHs[NI][NS];
    __shared__ double sKt[NI][NS];
    __shared__ double sGi[NI][NI];
    __shared__ double sPp[NS][NS];
    __shared__ double sx[2][NS];
    __shared__ double su[NI];

    const int tid  = threadIdx.x;
    const int wid  = tid >> 6, lane = tid & 63;
    const int pi   = tid >> 3, pj0 = (tid & 7) * 4, pb0 = (tid & 7) * 2;
    const int ki   = tid >> 4, kj0 = (tid & 15) * 2;

    for (int idx = tid; idx < NS * NS; idx += 256) sA[idx >> 5][idx & 31] = (double)Ag[idx];
    for (int idx = tid; idx < NS * NI; idx += 256) sB[idx >> 4][idx & 15] = (double)Bg[idx];
    __syncthreads();

    auto step = [&](int t, bool storeK, int kbase, bool emitMu) {
        const float* Ct = Cg + t * NA * NA;
        {
            double a0 = 0, a1 = 0, a2 = 0, a3 = 0, b0 = 0, b1 = 0;
            for (int k = 0; k < NS; ++k) {
                const double p = sP[pi][k];
                a0 += p * sA[k][pj0 + 0]; a1 += p * sA[k][pj0 + 1];
                a2 += p * sA[k][pj0 + 2]; a3 += p * sA[k][pj0 + 3];
                b0 += p * sB[k][pb0 + 0]; b1 += p * sB[k][pb0 + 1];
            }
            sPA[pi][pj0 + 0] = a0; sPA[pi][pj0 + 1] = a1;
            sPA[pi][pj0 + 2] = a2; sPA[pi][pj0 + 3] = a3;
            sPB[pi][pb0 + 0] = b0; sPB[pi][pb0 + 1] = b1;
        }
        __syncthreads();
        if (wid == 0) {
            const int ri = lane & 15, cg = lane >> 4, jb = cg * 4;
            double g0 = (double)Ct[(NS + ri) * NA + NS + jb + 0];
            double g1 = (double)Ct[(NS + ri) * NA + NS + jb + 1];
            double g2 = (double)Ct[(NS + ri) * NA + NS + jb + 2];
            double g3 = (double)Ct[(NS + ri) * NA + NS + jb + 3];
            for (int k = 0; k < NS; ++k) {
                const double b = sB[k][ri];
                g0 += b * sPB[k][jb + 0]; g1 += b * sPB[k][jb + 1];
                g2 += b * sPB[k][jb + 2]; g3 += b * sPB[k][jb + 3];
            }
#pragma unroll
            for (int k = 0; k < NI; ++k) {
                const double myslot = ((k & 3) == 0) ? g0 : ((k & 3) == 1) ? g1
                                     : ((k & 3) == 2) ? g2 : g3;
                const int    plv  = k + ((k >> 2) << 4);
                const double piv  = __shfl(myslot, plv, 64);
                const double cv   = __shfl(myslot, ri + ((k >> 2) << 4), 64);
                const double pr0  = __shfl(g0, k + (cg << 4), 64);
                const double pr1  = __shfl(g1, k + (cg << 4), 64);
                const double pr2  = __shfl(g2, k + (cg << 4), 64);
                const double pr3  = __shfl(g3, k + (cg << 4), 64);
                const double ip   = 1.0 / piv;
                const bool   rk   = (ri == k);
                g0 = rk ? ((jb + 0 == k) ? ip : pr0 * ip)
                        : ((jb + 0 == k) ? -cv * ip : g0 - cv * pr0 * ip);
                g1 = rk ? ((jb + 1 == k) ? ip : pr1 * ip)
                        : ((jb + 1 == k) ? -cv * ip : g1 - cv * pr1 * ip);
                g2 = rk ? ((jb + 2 == k) ? ip : pr2 * ip)
                        : ((jb + 2 == k) ? -cv * ip : g2 - cv * pr2 * ip);
                g3 = rk ? ((jb + 3 == k) ? ip : pr3 * ip)
                        : ((jb + 3 == k) ? -cv * ip : g3 - cv * pr3 * ip);
            }
            sGi[ri][jb + 0] = g0; sGi[ri][jb + 1] = g1;
            sGi[ri][jb + 2] = g2; sGi[ri][jb + 3] = g3;
        } else {
            const int e0 = tid - 64;
            for (int e = e0; e < NI * NS; e += 192) {
                const int i = e >> 5, j = e & 31;
                double acc = (double)Ct[j * NA + NS + i];
                for (int k = 0; k < NS; ++k) acc += sB[k][i] * sPA[k][j];
                sHs[i][j] = acc;
            }
            for (int e = e0; e < NS * NS; e += 192) {
                const int i = e >> 5, j = e & 31;
                double acc = (double)Ct[i * NA + j];
                for (int k = 0; k < NS; ++k) acc += sA[k][i] * sPA[k][j];
                sPp[i][j] = acc;
            }
        }
        __syncthreads();
        {
            double a0 = 0, a1 = 0;
            for (int k = 0; k < NI; ++k) {
                const double g = sGi[ki][k];
                a0 += g * sHs[k][kj0 + 0];
                a1 += g * sHs[k][kj0 + 1];
            }
            sKt[ki][kj0 + 0] = a0; sKt[ki][kj0 + 1] = a1;
            if (storeK) {
                sKh[t - kbase][ki][kj0 + 0] = (float)a0;
                sKh[t - kbase][ki][kj0 + 1] = (float)a1;
            }
        }
        __syncthreads();
        {
            double a0 = sPp[pi][pj0 + 0], a1 = sPp[pi][pj0 + 1];
            double a2 = sPp[pi][pj0 + 2], a3 = sPp[pi][pj0 + 3];
            for (int k = 0; k < NI; ++k) {
                const double h = sHs[k][pi];
                a0 -= h * sKt[k][pj0 + 0]; a1 -= h * sKt[k][pj0 + 1];
                a2 -= h * sKt[k][pj0 + 2]; a3 -= h * sKt[k][pj0 + 3];
            }
            double b0 = sPp[pj0 + 0][pi], b1 = sPp[pj0 + 1][pi];
            double b2 = sPp[pj0 + 2][pi], b3 = sPp[pj0 + 3][pi];
            for (int k = 0; k < NI; ++k) {
                const double hk = sKt[k][pi];
                b0 -= sHs[k][pj0 + 0] * hk; b1 -= sHs[k][pj0 + 1] * hk;
                b2 -= sHs[k][pj0 + 2] * hk; b3 -= sHs[k][pj0 + 3] * hk;
            }
            sP[pi][pj0 + 0] = 0.5 * (a0 + b0); sP[pi][pj0 + 1] = 0.5 * (a1 + b1);
            sP[pi][pj0 + 2] = 0.5 * (a2 + b2); sP[pi][pj0 + 3] = 0.5 * (a3 + b3);
        }
        __syncthreads();
        if (emitMu && tid < NS) {
            double acc = 0.0;
            for (int k = 0; k < NS; ++k) acc += sP[tid][k] * (double)sXT[t][k];
            if (t == 0) acc = -acc;
            out[NA * TT + t * NS + tid] = (float)acc;
        }
    };

    auto sweep = [&](int tlo, int klo, int khi, bool emitMu) {
        for (int idx = tid; idx < NS * NS; idx += 256) sP[idx >> 5][idx & 31] = 0.0;
        __syncthreads();
        for (int t = TT - 1; t >= tlo; --t)
            step(t, (t >= klo && t < khi), klo, emitMu);
    };

    int cur = 0;
    auto forward = [&](int t0, int t1, int kbase) {
        for (int t = t0; t < t1; ++t) {
            if (tid < NS) {
                const float xv = (float)sx[cur][tid];
                sXT[t][tid] = xv;
                out[t * NA + tid] = xv;
            } else if (tid >= 64 && tid < 64 + NI) {
                const int i = tid - 64;
                double acc = 0.0;
                for (int k = 0; k < NS; ++k)
                    acc += (double)sKh[t - kbase][i][k] * sx[cur][k];
                su[i] = -acc;
                out[t * NA + NS + i] = (float)(-acc);
            }
            __syncthreads();
            if (t < TT - 1) {
                if (tid < NS) {
                    double acc = 0.0;
                    for (int k = 0; k < NS; ++k) acc += sA[tid][k] * sx[cur][k];
                    for (int k = 0; k < NI; ++k) acc += sB[tid][k] * su[k];
                    sx[cur ^ 1][tid] = acc;
                }
                __syncthreads();
                cur ^= 1;
            }
        }
    };

    sweep(0, 0, HT, false);
    if (tid < NS) sx[0][tid] = (double)x0g[tid];
    __syncthreads();
    forward(0, HT, 0);
    sweep(HT, HT, TT, false);
    forward(HT, TT, HT);
    sweep(0, 0, 0, true);
}

extern "C" void kernel_launch(void* const* d_in, const int* in_sizes, int n_in,
                              void* d_out, int out_size, void* d_ws, size_t ws_size,
                              hipStream_t stream) {
    // Bind by element count (A=1024, B=512, C=147456, x0=32), fallback dict order.
    const float *A = nullptr, *B = nullptr, *C = nullptr, *x0 = nullptr;
    for (int i = 0; i < n_in; ++i) {
        switch (in_sizes[i]) {
            case 1024:   A  = (const float*)d_in[i]; break;
            case 512:    B  = (const float*)d_in[i]; break;
            case 147456: C  = (const float*)d_in[i]; break;
            case 32:     x0 = (const float*)d_in[i]; break;
            default: break;
        }
    }
    if (!A || !B || !C || !x0) {
        A  = (const float*)d_in[0];
        B  = (const float*)d_in[1];
        C  = (const float*)d_in[2];
        x0 = (const float*)d_in[5];
    }

    const size_t need = (size_t)(TT * NI * NS + TT * NS * NS) * sizeof(float); // 384 KB
    if (d_ws != nullptr && ws_size >= need) {
        float* Kall = (float*)d_ws;
        float* Pall = Kall + TT * NI * NS;
        lqr_fast<<<1, 1024, 0, stream>>>(A, B, C, x0, (float*)d_out, Kall, Pall);
    } else {
        lqr_kernel_fb<<<1, 256, 0, stream>>>(A, B, C, x0, (float*)d_out);
    }
}

// Round 15
// 637.480 us; speedup vs baseline: 1.2911x; 1.2911x over previous
//
#include <hip/hip_runtime.h>

#define NS 32   // n_state
#define NI 16   // n_input
#define NA 48   // n_all
#define TT 64   // horizon
#define HT 32   // half horizon
#define CSZ (NA * NA)      // 2304 floats per C_t

// f64 reciprocal: f32 rcp seed + 2 Newton steps (~1 ulp; GJ margin ~1000x)
__device__ __forceinline__ double fast_rcp(double x) {
    double r = (double)(1.0f / (float)x);
    r = r * (2.0 - x * r);
    r = r * (2.0 - x * r);
    return r;
}

// ---------------- FAST PATH ----------------
// 256 threads (r12-proven layout: ILP-per-thread beats TLP here — r14's
// 1024-thread 1-elem layout regressed 586->823). Single backward sweep
// (64 steps, 4 barriers), K_t/P_t (f32) to d_ws; single-wave shfl forward;
// parallel mu pass. Phase 2 restructured for ILP: fused Hs+Pp 4-col tasks.
// Numerics bit-identical to rounds 9-14: f64 state, ascending-k dots, fused
// exact symmetrization (REQUIRED — unsymmetrized diverges, 126976 sig),
// register/__shfl GJ in wave 0, f32 out.
__launch_bounds__(256, 1)
__global__ void lqr_fast(const float* __restrict__ Ag,
                         const float* __restrict__ Bg,
                         const float* __restrict__ Cg,
                         const float* __restrict__ x0g,
                         float* __restrict__ out,
                         float* __restrict__ Kall,   // [TT][NI][NS] f32
                         float* __restrict__ Pall)   // [TT][NS][NS] f32
{
    __shared__ float  sXT[TT][NS];      //  8192 B  x trajectory (f32)
    __shared__ double sA[NS][33];       //  8448 B  (odd strides: conflict-free)
    __shared__ double sB[NS][17];       //  4352 B
    __shared__ double sP[NS][33];       //  8448 B  Riccati state (f64)
    __shared__ double sPA[NS][33];      //  8448 B  P*A
    __shared__ double sPB[NS][17];      //  4352 B  P*B
    __shared__ double sHs[NI][33];      //  4224 B  S^T + B^T P A
    __shared__ double sKt[NI][33];      //  4224 B  K_t (f64)
    __shared__ double sGi[NI][17];      //  2176 B  G^{-1}
    __shared__ double sPp[NS][33];      //  8448 B  Q + A^T P A  (~53 KB)

    const int tid  = threadIdx.x;
    const int wid  = tid >> 6, lane = tid & 63;
    const int pi   = tid >> 3, pj0 = (tid & 7) * 4, pb0 = (tid & 7) * 2;
    const int ki   = tid >> 4, kj0 = (tid & 15) * 2;

    for (int idx = tid; idx < NS * NS; idx += 256) {
        sA[idx >> 5][idx & 31] = (double)Ag[idx];
        sP[idx >> 5][idx & 31] = 0.0;
    }
    for (int idx = tid; idx < NS * NI; idx += 256)
        sB[idx >> 4][idx & 15] = (double)Bg[idx];
    __syncthreads();

    // ---- backward sweep: 64 steps, 4 barriers each ----
    for (int t = TT - 1; t >= 0; --t) {
        const float* Ct = Cg + t * CSZ;

        // phase 1: PA = P*A (4 cols) + PB = P*B (2 cols) per thread (ILP-6)
        {
            double a0 = 0, a1 = 0, a2 = 0, a3 = 0, b0 = 0, b1 = 0;
#pragma unroll 8
            for (int k = 0; k < NS; ++k) {
                const double p = sP[pi][k];
                a0 += p * sA[k][pj0 + 0]; a1 += p * sA[k][pj0 + 1];
                a2 += p * sA[k][pj0 + 2]; a3 += p * sA[k][pj0 + 3];
                b0 += p * sB[k][pb0 + 0]; b1 += p * sB[k][pb0 + 1];
            }
            sPA[pi][pj0 + 0] = a0; sPA[pi][pj0 + 1] = a1;
            sPA[pi][pj0 + 2] = a2; sPA[pi][pj0 + 3] = a3;
            sPB[pi][pb0 + 0] = b0; sPB[pi][pb0 + 1] = b1;
        }
        __syncthreads();                                   // barrier A

        // phase 2 (overlapped, ILP-restructured):
        //   wave 0          : G = R + B^T P B -> G^{-1} (register GJ, __shfl)
        //   threads 64..191 : Hs[i][j0..j0+3] AND Pp[i][j0..j0+3] (rows 0..15),
        //                     fused k-loop, shared sPA reads (8 acc, ILP-8)
        //   threads 192..255: Pp rows 16..31, 8-col blocks (8 acc, ILP-8)
        if (wid == 0) {
            const int ri = lane & 15, cg = lane >> 4, jb = cg * 4;
            double g0 = (double)Ct[(NS + ri) * NA + NS + jb + 0];
            double g1 = (double)Ct[(NS + ri) * NA + NS + jb + 1];
            double g2 = (double)Ct[(NS + ri) * NA + NS + jb + 2];
            double g3 = (double)Ct[(NS + ri) * NA + NS + jb + 3];
#pragma unroll 8
            for (int k = 0; k < NS; ++k) {
                const double b = sB[k][ri];
                g0 += b * sPB[k][jb + 0]; g1 += b * sPB[k][jb + 1];
                g2 += b * sPB[k][jb + 2]; g3 += b * sPB[k][jb + 3];
            }
#pragma unroll
            for (int k = 0; k < NI; ++k) {
                const double myslot = ((k & 3) == 0) ? g0 : ((k & 3) == 1) ? g1
                                     : ((k & 3) == 2) ? g2 : g3;
                const int    plv  = k + ((k >> 2) << 4);      // lane of (k,k)
                const double piv  = __shfl(myslot, plv, 64);
                const double cv   = __shfl(myslot, ri + ((k >> 2) << 4), 64); // (ri,k)
                const double pr0  = __shfl(g0, k + (cg << 4), 64);            // (k,jb+j)
                const double pr1  = __shfl(g1, k + (cg << 4), 64);
                const double pr2  = __shfl(g2, k + (cg << 4), 64);
                const double pr3  = __shfl(g3, k + (cg << 4), 64);
                const double ip   = fast_rcp(piv);
                const bool   rk   = (ri == k);
                g0 = rk ? ((jb + 0 == k) ? ip : pr0 * ip)
                        : ((jb + 0 == k) ? -cv * ip : g0 - cv * pr0 * ip);
                g1 = rk ? ((jb + 1 == k) ? ip : pr1 * ip)
                        : ((jb + 1 == k) ? -cv * ip : g1 - cv * pr1 * ip);
                g2 = rk ? ((jb + 2 == k) ? ip : pr2 * ip)
                        : ((jb + 2 == k) ? -cv * ip : g2 - cv * pr2 * ip);
                g3 = rk ? ((jb + 3 == k) ? ip : pr3 * ip)
                        : ((jb + 3 == k) ? -cv * ip : g3 - cv * pr3 * ip);
            }
            sGi[ri][jb + 0] = g0; sGi[ri][jb + 1] = g1;
            sGi[ri][jb + 2] = g2; sGi[ri][jb + 3] = g3;
        } else if (tid < 192) {
            const int q  = tid - 64;            // 0..127
            const int i  = q >> 3;              // 0..15
            const int j0 = (q & 7) * 4;         // 0,4,..,28
            double h0 = (double)Ct[(j0 + 0) * NA + NS + i];
            double h1 = (double)Ct[(j0 + 1) * NA + NS + i];
            double h2 = (double)Ct[(j0 + 2) * NA + NS + i];
            double h3 = (double)Ct[(j0 + 3) * NA + NS + i];
            double p0 = (double)Ct[i * NA + j0 + 0];
            double p1 = (double)Ct[i * NA + j0 + 1];
            double p2 = (double)Ct[i * NA + j0 + 2];
            double p3 = (double)Ct[i * NA + j0 + 3];
#pragma unroll 8
            for (int k = 0; k < NS; ++k) {
                const double bm = sB[k][i];
                const double am = sA[k][i];
                const double v0 = sPA[k][j0 + 0], v1 = sPA[k][j0 + 1];
                const double v2 = sPA[k][j0 + 2], v3 = sPA[k][j0 + 3];
                h0 += bm * v0; h1 += bm * v1; h2 += bm * v2; h3 += bm * v3;
                p0 += am * v0; p1 += am * v1; p2 += am * v2; p3 += am * v3;
            }
            sHs[i][j0 + 0] = h0; sHs[i][j0 + 1] = h1;
            sHs[i][j0 + 2] = h2; sHs[i][j0 + 3] = h3;
            sPp[i][j0 + 0] = p0; sPp[i][j0 + 1] = p1;
            sPp[i][j0 + 2] = p2; sPp[i][j0 + 3] = p3;
        } else {
            const int s  = tid - 192;           // 0..63
            const int i  = 16 + (s >> 2);       // 16..31
            const int j0 = (s & 3) * 8;         // 0,8,16,24
            double p0 = (double)Ct[i * NA + j0 + 0];
            double p1 = (double)Ct[i * NA + j0 + 1];
            double p2 = (double)Ct[i * NA + j0 + 2];
            double p3 = (double)Ct[i * NA + j0 + 3];
            double p4 = (double)Ct[i * NA + j0 + 4];
            double p5 = (double)Ct[i * NA + j0 + 5];
            double p6 = (double)Ct[i * NA + j0 + 6];
            double p7 = (double)Ct[i * NA + j0 + 7];
#pragma unroll 8
            for (int k = 0; k < NS; ++k) {
                const double am = sA[k][i];
                p0 += am * sPA[k][j0 + 0]; p1 += am * sPA[k][j0 + 1];
                p2 += am * sPA[k][j0 + 2]; p3 += am * sPA[k][j0 + 3];
                p4 += am * sPA[k][j0 + 4]; p5 += am * sPA[k][j0 + 5];
                p6 += am * sPA[k][j0 + 6]; p7 += am * sPA[k][j0 + 7];
            }
            sPp[i][j0 + 0] = p0; sPp[i][j0 + 1] = p1;
            sPp[i][j0 + 2] = p2; sPp[i][j0 + 3] = p3;
            sPp[i][j0 + 4] = p4; sPp[i][j0 + 5] = p5;
            sPp[i][j0 + 6] = p6; sPp[i][j0 + 7] = p7;
        }
        __syncthreads();                                   // barrier B

        // phase 3: K = G^{-1} Hs (2 cols per thread, ILP-2, full unroll)
        {
            double a0 = 0, a1 = 0;
#pragma unroll
            for (int k = 0; k < NI; ++k) {
                const double g = sGi[ki][k];
                a0 += g * sHs[k][kj0 + 0];
                a1 += g * sHs[k][kj0 + 1];
            }
            sKt[ki][kj0 + 0] = a0; sKt[ki][kj0 + 1] = a1;
            Kall[t * NI * NS + ki * NS + kj0 + 0] = (float)a0;
            Kall[t * NI * NS + ki * NS + kj0 + 1] = (float)a1;
        }
        __syncthreads();                                   // barrier C

        // phase 4: P_t = sym(Pp - Hs^T K) (ILP-8, full unroll)
        {
            double a0 = sPp[pi][pj0 + 0], a1 = sPp[pi][pj0 + 1];
            double a2 = sPp[pi][pj0 + 2], a3 = sPp[pi][pj0 + 3];
            double b0 = sPp[pj0 + 0][pi], b1 = sPp[pj0 + 1][pi];
            double b2 = sPp[pj0 + 2][pi], b3 = sPp[pj0 + 3][pi];
#pragma unroll
            for (int k = 0; k < NI; ++k) {
                const double h  = sHs[k][pi];
                const double hk = sKt[k][pi];
                a0 -= h * sKt[k][pj0 + 0]; a1 -= h * sKt[k][pj0 + 1];
                a2 -= h * sKt[k][pj0 + 2]; a3 -= h * sKt[k][pj0 + 3];
                b0 -= sHs[k][pj0 + 0] * hk; b1 -= sHs[k][pj0 + 1] * hk;
                b2 -= sHs[k][pj0 + 2] * hk; b3 -= sHs[k][pj0 + 3] * hk;
            }
            const double r0 = 0.5 * (a0 + b0), r1 = 0.5 * (a1 + b1);
            const double r2 = 0.5 * (a2 + b2), r3 = 0.5 * (a3 + b3);
            sP[pi][pj0 + 0] = r0; sP[pi][pj0 + 1] = r1;
            sP[pi][pj0 + 2] = r2; sP[pi][pj0 + 3] = r3;
            float* Pt = Pall + t * NS * NS + pi * NS + pj0;
            Pt[0] = (float)r0; Pt[1] = (float)r1; Pt[2] = (float)r2; Pt[3] = (float)r3;
        }
        __syncthreads();                                   // barrier D
    }

    // ---- forward rollout: single wave, x in registers, shfl broadcast ----
    if (wid == 0) {
        const int row = lane & 31;
        double x = 0.0;
        if (lane < NS) x = (double)x0g[lane];
        for (int t = 0; t < TT; ++t) {
            if (lane < NS) {
                const float xv = (float)x;
                sXT[t][lane] = xv;
                out[t * NA + lane] = xv;
            }
            const float* Kt = Kall + t * NI * NS + (lane & 15) * NS;
            double accU = 0.0;
#pragma unroll 8
            for (int k = 0; k < NS; ++k) {
                const double xk = __shfl(x, k, 64);
                accU += (double)Kt[k] * xk;
            }
            const double u = -accU;
            if (lane < NI) out[t * NA + NS + lane] = (float)u;
            if (t < TT - 1) {
                double accX = 0.0;
#pragma unroll 8
                for (int k = 0; k < NS; ++k) {
                    const double xk = __shfl(x, k, 64);
                    accX += sA[row][k] * xk;
                }
#pragma unroll 8
                for (int k = 0; k < NI; ++k) {
                    const double uk = __shfl(u, k, 64);   // lane k holds u row k
                    accX += sB[row][k] * uk;
                }
                x = accX;
            }
        }
    }
    __syncthreads();

    // ---- mu pass: mu_t = P_t x_t (2048 parallel dots); mu_0 negated ----
    for (int e = tid; e < TT * NS; e += 256) {
        const int t = e >> 5, i = e & 31;
        const float* Pt = Pall + t * NS * NS + i * NS;
        double acc = 0.0;
#pragma unroll 8
        for (int k = 0; k < NS; ++k) acc += (double)Pt[k] * (double)sXT[t][k];
        if (t == 0) acc = -acc;
        out[NA * TT + t * NS + i] = (float)acc;
    }
}

// ---------------- FALLBACK (round-11/12, passing) — if ws_size < 384 KB ----
__launch_bounds__(256, 1)
__global__ void lqr_kernel_fb(const float* __restrict__ Ag,
                              const float* __restrict__ Bg,
                              const float* __restrict__ Cg,
                              const float* __restrict__ x0g,
                              float* __restrict__ out)
{
    __shared__ float  sKh[HT][NI][NS];
    __shared__ float  sXT[TT][NS];
    __shared__ double sA[NS][NS];
    __shared__ double sB[NS][NI];
    __shared__ double sP[NS][NS];
    __shared__ double sPA[NS][NS];
    __shared__ double sPB[NS][NI];
    __shared__ double sHs[NI][NS];
    __shared__ double sKt[NI][NS];
    __shared__ double sGi[NI][NI];
    __shared__ double sPp[NS][NS];
    __shared__ double sx[2][NS];
    __shared__ double su[NI];

    const int tid  = threadIdx.x;
    const int wid  = tid >> 6, lane = tid & 63;
    const int pi   = tid >> 3, pj0 = (tid & 7) * 4, pb0 = (tid & 7) * 2;
    const int ki   = tid >> 4, kj0 = (tid & 15) * 2;

    for (int idx = tid; idx < NS * NS; idx += 256) sA[idx >> 5][idx & 31] = (double)Ag[idx];
    for (int idx = tid; idx < NS * NI; idx += 256) sB[idx >> 4][idx & 15] = (double)Bg[idx];
    __syncthreads();

    auto step = [&](int t, bool storeK, int kbase, bool emitMu) {
        const float* Ct = Cg + t * NA * NA;
        {
            double a0 = 0, a1 = 0, a2 = 0, a3 = 0, b0 = 0, b1 = 0;
            for (int k = 0; k < NS; ++k) {
                const double p = sP[pi][k];
                a0 += p * sA[k][pj0 + 0]; a1 += p * sA[k][pj0 + 1];
                a2 += p * sA[k][pj0 + 2]; a3 += p * sA[k][pj0 + 3];
                b0 += p * sB[k][pb0 + 0]; b1 += p * sB[k][pb0 + 1];
            }
            sPA[pi][pj0 + 0] = a0; sPA[pi][pj0 + 1] = a1;
            sPA[pi][pj0 + 2] = a2; sPA[pi][pj0 + 3] = a3;
            sPB[pi][pb0 + 0] = b0; sPB[pi][pb0 + 1] = b1;
        }
        __syncthreads();
        if (wid == 0) {
            const int ri = lane & 15, cg = lane >> 4, jb = cg * 4;
            double g0 = (double)Ct[(NS + ri) * NA + NS + jb + 0];
            double g1 = (double)Ct[(NS + ri) * NA + NS + jb + 1];
            double g2 = (double)Ct[(NS + ri) * NA + NS + jb + 2];
            double g3 = (double)Ct[(NS + ri) * NA + NS + jb + 3];
            for (int k = 0; k < NS; ++k) {
                const double b = sB[k][ri];
                g0 += b * sPB[k][jb + 0]; g1 += b * sPB[k][jb + 1];
                g2 += b * sPB[k][jb + 2]; g3 += b * sPB[k][jb + 3];
            }
#pragma unroll
            for (int k = 0; k < NI; ++k) {
                const double myslot = ((k & 3) == 0) ? g0 : ((k & 3) == 1) ? g1
                                     : ((k & 3) == 2) ? g2 : g3;
                const int    plv  = k + ((k >> 2) << 4);
                const double piv  = __shfl(myslot, plv, 64);
                const double cv   = __shfl(myslot, ri + ((k >> 2) << 4), 64);
                const double pr0  = __shfl(g0, k + (cg << 4), 64);
                const double pr1  = __shfl(g1, k + (cg << 4), 64);
                const double pr2  = __shfl(g2, k + (cg << 4), 64);
                const double pr3  = __shfl(g3, k + (cg << 4), 64);
                const double ip   = 1.0 / piv;
                const bool   rk   = (ri == k);
                g0 = rk ? ((jb + 0 == k) ? ip : pr0 * ip)
                        : ((jb + 0 == k) ? -cv * ip : g0 - cv * pr0 * ip);
                g1 = rk ? ((jb + 1 == k) ? ip : pr1 * ip)
                        : ((jb + 1 == k) ? -cv * ip : g1 - cv * pr1 * ip);
                g2 = rk ? ((jb + 2 == k) ? ip : pr2 * ip)
                        : ((jb + 2 == k) ? -cv * ip : g2 - cv * pr2 * ip);
                g3 = rk ? ((jb + 3 == k) ? ip : pr3 * ip)
                        : ((jb + 3 == k) ? -cv * ip : g3 - cv * pr3 * ip);
            }
            sGi[ri][jb + 0] = g0; sGi[ri][jb + 1] = g1;
            sGi[ri][jb + 2] = g2; sGi[ri][jb + 3] = g3;
        } else {
            const int e0 = tid - 64;
            for (int e = e0; e < NI * NS; e += 192) {
                const int i = e >> 5, j = e & 31;
                double acc = (double)Ct[j * NA + NS + i];
                for (int k = 0; k < NS; ++k) acc += sB[k][i] * sPA[k][j];
                sHs[i][j] = acc;
            }
            for (int e = e0; e < NS * NS; e += 192) {
                const int i = e >> 5, j = e & 31;
                double acc = (double)Ct[i * NA + j];
                for (int k = 0; k < NS; ++k) acc += sA[k][i] * sPA[k][j];
                sPp[i][j] = acc;
            }
        }
        __syncthreads();
        {
            double a0 = 0, a1 = 0;
            for (int k = 0; k < NI; ++k) {
                const double g = sGi[ki][k];
                a0 += g * sHs[k][kj0 + 0];
                a1 += g * sHs[k][kj0 + 1];
            }
            sKt[ki][kj0 + 0] = a0; sKt[ki][kj0 + 1] = a1;
            if (storeK) {
                sKh[t - kbase][ki][kj0 + 0] = (float)a0;
                sKh[t - kbase][ki][kj0 + 1] = (float)a1;
            }
        }
        __syncthreads();
        {
            double a0 = sPp[pi][pj0 + 0], a1 = sPp[pi][pj0 + 1];
            double a2 = sPp[pi][pj0 + 2], a3 = sPp[pi][pj0 + 3];
            for (int k = 0; k < NI; ++k) {
                const double h = sHs[k][pi];
                a0 -= h * sKt[k][pj0 + 0]; a1 -= h * sKt[k][pj0 + 1];
                a2 -= h * sKt[k][pj0 + 2]; a3 -= h * sKt[k][pj0 + 3];
            }
            double b0 = sPp[pj0 + 0][pi], b1 = sPp[pj0 + 1][pi];
            double b2 = sPp[pj0 + 2][pi], b3 = sPp[pj0 + 3][pi];
            for (int k = 0; k < NI; ++k) {
                const double hk = sKt[k][pi];
                b0 -= sHs[k][pj0 + 0] * hk; b1 -= sHs[k][pj0 + 1] * hk;
                b2 -= sHs[k][pj0 + 2] * hk; b3 -= sHs[k][pj0 + 3] * hk;
            }
            sP[pi][pj0 + 0] = 0.5 * (a0 + b0); sP[pi][pj0 + 1] = 0.5 * (a1 + b1);
            sP[pi][pj0 + 2] = 0.5 * (a2 + b2); sP[pi][pj0 + 3] = 0.5 * (a3 + b3);
        }
        __syncthreads();
        if (emitMu && tid < NS) {
            double acc = 0.0;
            for (int k = 0; k < NS; ++k) acc += sP[tid][k] * (double)sXT[t][k];
            if (t == 0) acc = -acc;
            out[NA * TT + t * NS + tid] = (float)acc;
        }
    };

    auto sweep = [&](int tlo, int klo, int khi, bool emitMu) {
        for (int idx = tid; idx < NS * NS; idx += 256) sP[idx >> 5][idx & 31] = 0.0;
        __syncthreads();
        for (int t = TT - 1; t >= tlo; --t)
            step(t, (t >= klo && t < khi), klo, emitMu);
    };

    int cur = 0;
    auto forward = [&](int t0, int t1, int kbase) {
        for (int t = t0; t < t1; ++t) {
            if (tid < NS) {
                const float xv = (float)sx[cur][tid];
                sXT[t][tid] = xv;
                out[t * NA + tid] = xv;
            } else if (tid >= 64 && tid < 64 + NI) {
                const int i = tid - 64;
                double acc = 0.0;
                for (int k = 0; k < NS; ++k)
                    acc += (double)sKh[t - kbase][i][k] * sx[cur][k];
                su[i] = -acc;
                out[t * NA + NS + i] = (float)(-acc);
            }
            __syncthreads();
            if (t < TT - 1) {
                if (tid < NS) {
                    double acc = 0.0;
                    for (int k = 0; k < NS; ++k) acc += sA[tid][k] * sx[cur][k];
                    for (int k = 0; k < NI; ++k) acc += sB[tid][k] * su[k];
                    sx[cur ^ 1][tid] = acc;
                }
                __syncthreads();
                cur ^= 1;
            }
        }
    };

    sweep(0, 0, HT, false);
    if (tid < NS) sx[0][tid] = (double)x0g[tid];
    __syncthreads();
    forward(0, HT, 0);
    sweep(HT, HT, TT, false);
    forward(HT, TT, HT);
    sweep(0, 0, 0, true);
}

extern "C" void kernel_launch(void* const* d_in, const int* in_sizes, int n_in,
                              void* d_out, int out_size, void* d_ws, size_t ws_size,
                              hipStream_t stream) {
    // Bind by element count (A=1024, B=512, C=147456, x0=32), fallback dict order.
    const float *A = nullptr, *B = nullptr, *C = nullptr, *x0 = nullptr;
    for (int i = 0; i < n_in; ++i) {
        switch (in_sizes[i]) {
            case 1024:   A  = (const float*)d_in[i]; break;
            case 512:    B  = (const float*)d_in[i]; break;
            case 147456: C  = (const float*)d_in[i]; break;
            case 32:     x0 = (const float*)d_in[i]; break;
            default: break;
        }
    }
    if (!A || !B || !C || !x0) {
        A  = (const float*)d_in[0];
        B  = (const float*)d_in[1];
        C  = (const float*)d_in[2];
        x0 = (const float*)d_in[5];
    }

    const size_t need = (size_t)(TT * NI * NS + TT * NS * NS) * sizeof(float); // 384 KB
    if (d_ws != nullptr && ws_size >= need) {
        float* Kall = (float*)d_ws;
        float* Pall = Kall + TT * NI * NS;
        lqr_fast<<<1, 256, 0, stream>>>(A, B, C, x0, (float*)d_out, Kall, Pall);
    } else {
        lqr_kernel_fb<<<1, 256, 0, stream>>>(A, B, C, x0, (float*)d_out);
    }
}

// Round 16
// 564.194 us; speedup vs baseline: 1.4588x; 1.1299x over previous
//
#include <hip/hip_runtime.h>

#define NS 32   // n_state
#define NI 16   // n_input
#define NA 48   // n_all
#define TT 64   // horizon
#define HT 32   // half horizon
#define CSZ (NA * NA)      // 2304 floats per C_t

// ---------------- FAST PATH ----------------
// Round-12 structure verbatim (best: 586 us) with ONE change: A,B stored in
// LDS as f32 (input data is f32 -> f64 promotion exact -> bit-identical math,
// ~40% less LDS traffic in the dominant phases).
// Single backward sweep (64 steps, 4 barriers), K_t/P_t (f32) to d_ws,
// barrier forward rollout, parallel mu pass. f64 Riccati state, fused exact
// symmetrization (REQUIRED - unsymmetrized diverges, 126976 signature).
__launch_bounds__(256, 1)
__global__ void lqr_fast(const float* __restrict__ Ag,
                         const float* __restrict__ Bg,
                         const float* __restrict__ Cg,
                         const float* __restrict__ x0g,
                         float* __restrict__ out,
                         float* __restrict__ Kall,   // [TT][NI][NS] f32
                         float* __restrict__ Pall)   // [TT][NS][NS] f32
{
    __shared__ float  sXT[TT][NS];      //  8192 B  x trajectory (f32)
    __shared__ float  sA[NS][33];       //  4224 B  A as f32 (exact input data)
    __shared__ float  sB[NS][17];       //  2176 B  B as f32 (exact input data)
    __shared__ double sP[NS][33];       //  8448 B  Riccati state (f64)
    __shared__ double sPA[NS][33];      //  8448 B  P*A
    __shared__ double sPB[NS][17];      //  4352 B  P*B
    __shared__ double sHs[NI][33];      //  4224 B  S^T + B^T P A
    __shared__ double sKt[NI][33];      //  4224 B  K_t (f64)
    __shared__ double sGi[NI][17];      //  2176 B  G^{-1}
    __shared__ double sPp[NS][33];      //  8448 B  Q + A^T P A
    __shared__ double sx[2][NS];        //   512 B
    __shared__ double su[NI];           //   128 B   (~55 KB)

    const int tid  = threadIdx.x;
    const int wid  = tid >> 6, lane = tid & 63;
    const int pi   = tid >> 3, pj0 = (tid & 7) * 4, pb0 = (tid & 7) * 2;
    const int ki   = tid >> 4, kj0 = (tid & 15) * 2;

    for (int idx = tid; idx < NS * NS; idx += 256) {
        sA[idx >> 5][idx & 31] = Ag[idx];
        sP[idx >> 5][idx & 31] = 0.0;
    }
    for (int idx = tid; idx < NS * NI; idx += 256)
        sB[idx >> 4][idx & 15] = Bg[idx];
    __syncthreads();

    // ---- backward sweep: 64 steps, 4 barriers each ----
    for (int t = TT - 1; t >= 0; --t) {
        const float* Ct = Cg + t * CSZ;

        // phase 1: PA = P*A (4 cols), PB = P*B (2 cols) per thread
        {
            double a0 = 0, a1 = 0, a2 = 0, a3 = 0, b0 = 0, b1 = 0;
            for (int k = 0; k < NS; ++k) {
                const double p = sP[pi][k];
                a0 += p * (double)sA[k][pj0 + 0]; a1 += p * (double)sA[k][pj0 + 1];
                a2 += p * (double)sA[k][pj0 + 2]; a3 += p * (double)sA[k][pj0 + 3];
                b0 += p * (double)sB[k][pb0 + 0]; b1 += p * (double)sB[k][pb0 + 1];
            }
            sPA[pi][pj0 + 0] = a0; sPA[pi][pj0 + 1] = a1;
            sPA[pi][pj0 + 2] = a2; sPA[pi][pj0 + 3] = a3;
            sPB[pi][pb0 + 0] = b0; sPB[pi][pb0 + 1] = b1;
        }
        __syncthreads();                                   // barrier A

        // phase 2 (overlapped): wave0 -> G^{-1} (register GJ via __shfl);
        //                       waves 1-3 -> Hs, Pp
        if (wid == 0) {
            const int ri = lane & 15, cg = lane >> 4, jb = cg * 4;
            double g0 = (double)Ct[(NS + ri) * NA + NS + jb + 0];
            double g1 = (double)Ct[(NS + ri) * NA + NS + jb + 1];
            double g2 = (double)Ct[(NS + ri) * NA + NS + jb + 2];
            double g3 = (double)Ct[(NS + ri) * NA + NS + jb + 3];
            for (int k = 0; k < NS; ++k) {
                const double b = (double)sB[k][ri];
                g0 += b * sPB[k][jb + 0]; g1 += b * sPB[k][jb + 1];
                g2 += b * sPB[k][jb + 2]; g3 += b * sPB[k][jb + 3];
            }
#pragma unroll
            for (int k = 0; k < NI; ++k) {
                const double myslot = ((k & 3) == 0) ? g0 : ((k & 3) == 1) ? g1
                                     : ((k & 3) == 2) ? g2 : g3;
                const int    plv  = k + ((k >> 2) << 4);      // lane of (k,k)
                const double piv  = __shfl(myslot, plv, 64);
                const double cv   = __shfl(myslot, ri + ((k >> 2) << 4), 64); // (ri,k)
                const double pr0  = __shfl(g0, k + (cg << 4), 64);            // (k,jb+j)
                const double pr1  = __shfl(g1, k + (cg << 4), 64);
                const double pr2  = __shfl(g2, k + (cg << 4), 64);
                const double pr3  = __shfl(g3, k + (cg << 4), 64);
                const double ip   = 1.0 / piv;
                const bool   rk   = (ri == k);
                g0 = rk ? ((jb + 0 == k) ? ip : pr0 * ip)
                        : ((jb + 0 == k) ? -cv * ip : g0 - cv * pr0 * ip);
                g1 = rk ? ((jb + 1 == k) ? ip : pr1 * ip)
                        : ((jb + 1 == k) ? -cv * ip : g1 - cv * pr1 * ip);
                g2 = rk ? ((jb + 2 == k) ? ip : pr2 * ip)
                        : ((jb + 2 == k) ? -cv * ip : g2 - cv * pr2 * ip);
                g3 = rk ? ((jb + 3 == k) ? ip : pr3 * ip)
                        : ((jb + 3 == k) ? -cv * ip : g3 - cv * pr3 * ip);
            }
            sGi[ri][jb + 0] = g0; sGi[ri][jb + 1] = g1;
            sGi[ri][jb + 2] = g2; sGi[ri][jb + 3] = g3;
        } else {
            const int e0 = tid - 64;
            for (int e = e0; e < NI * NS; e += 192) {
                const int i = e >> 5, j = e & 31;
                double acc = (double)Ct[j * NA + NS + i];
                for (int k = 0; k < NS; ++k) acc += (double)sB[k][i] * sPA[k][j];
                sHs[i][j] = acc;
            }
            for (int e = e0; e < NS * NS; e += 192) {
                const int i = e >> 5, j = e & 31;
                double acc = (double)Ct[i * NA + j];
                for (int k = 0; k < NS; ++k) acc += (double)sA[k][i] * sPA[k][j];
                sPp[i][j] = acc;
            }
        }
        __syncthreads();                                   // barrier B

        // phase 3: K = G^{-1} Hs (2 cols per thread); f32 K to d_ws
        {
            double a0 = 0, a1 = 0;
            for (int k = 0; k < NI; ++k) {
                const double g = sGi[ki][k];
                a0 += g * sHs[k][kj0 + 0];
                a1 += g * sHs[k][kj0 + 1];
            }
            sKt[ki][kj0 + 0] = a0; sKt[ki][kj0 + 1] = a1;
            Kall[t * NI * NS + ki * NS + kj0 + 0] = (float)a0;
            Kall[t * NI * NS + ki * NS + kj0 + 1] = (float)a1;
        }
        __syncthreads();                                   // barrier C

        // phase 4: P_t = sym(Pp - Hs^T K); f32 P to d_ws
        {
            double a0 = sPp[pi][pj0 + 0], a1 = sPp[pi][pj0 + 1];
            double a2 = sPp[pi][pj0 + 2], a3 = sPp[pi][pj0 + 3];
            for (int k = 0; k < NI; ++k) {
                const double h = sHs[k][pi];
                a0 -= h * sKt[k][pj0 + 0]; a1 -= h * sKt[k][pj0 + 1];
                a2 -= h * sKt[k][pj0 + 2]; a3 -= h * sKt[k][pj0 + 3];
            }
            double b0 = sPp[pj0 + 0][pi], b1 = sPp[pj0 + 1][pi];
            double b2 = sPp[pj0 + 2][pi], b3 = sPp[pj0 + 3][pi];
            for (int k = 0; k < NI; ++k) {
                const double hk = sKt[k][pi];
                b0 -= sHs[k][pj0 + 0] * hk; b1 -= sHs[k][pj0 + 1] * hk;
                b2 -= sHs[k][pj0 + 2] * hk; b3 -= sHs[k][pj0 + 3] * hk;
            }
            const double r0 = 0.5 * (a0 + b0), r1 = 0.5 * (a1 + b1);
            const double r2 = 0.5 * (a2 + b2), r3 = 0.5 * (a3 + b3);
            sP[pi][pj0 + 0] = r0; sP[pi][pj0 + 1] = r1;
            sP[pi][pj0 + 2] = r2; sP[pi][pj0 + 3] = r3;
            float* Pt = Pall + t * NS * NS + pi * NS + pj0;
            Pt[0] = (float)r0; Pt[1] = (float)r1; Pt[2] = (float)r2; Pt[3] = (float)r3;
        }
        __syncthreads();                                   // barrier D
    }

    // ---- forward rollout: tau (x + u), record x trajectory ----
    if (tid < NS) sx[0][tid] = (double)x0g[tid];
    __syncthreads();
    int cur = 0;
    for (int t = 0; t < TT; ++t) {
        if (tid < NS) {
            const float xv = (float)sx[cur][tid];
            sXT[t][tid] = xv;
            out[t * NA + tid] = xv;
        } else if (tid >= 64 && tid < 64 + NI) {
            const int i = tid - 64;
            const float* Kt = Kall + t * NI * NS + i * NS;
            double acc = 0.0;
            for (int k = 0; k < NS; ++k) acc += (double)Kt[k] * sx[cur][k];
            su[i] = -acc;
            out[t * NA + NS + i] = (float)(-acc);
        }
        __syncthreads();
        if (t < TT - 1) {
            if (tid < NS) {
                double acc = 0.0;
                for (int k = 0; k < NS; ++k) acc += (double)sA[tid][k] * sx[cur][k];
                for (int k = 0; k < NI; ++k) acc += (double)sB[tid][k] * su[k];
                sx[cur ^ 1][tid] = acc;
            }
            __syncthreads();
            cur ^= 1;
        }
    }
    __syncthreads();

    // ---- mu pass: mu_t = P_t x_t (2048 parallel dots); mu_0 negated ----
    for (int e = tid; e < TT * NS; e += 256) {
        const int t = e >> 5, i = e & 31;
        const float* Pt = Pall + t * NS * NS + i * NS;
        double acc = 0.0;
        for (int k = 0; k < NS; ++k) acc += (double)Pt[k] * (double)sXT[t][k];
        if (t == 0) acc = -acc;
        out[NA * TT + t * NS + i] = (float)acc;
    }
}

// ---------------- FALLBACK (round-11/12, passing) — if ws_size < 384 KB ----
__launch_bounds__(256, 1)
__global__ void lqr_kernel_fb(const float* __restrict__ Ag,
                              const float* __restrict__ Bg,
                              const float* __restrict__ Cg,
                              const float* __restrict__ x0g,
                              float* __restrict__ out)
{
    __shared__ float  sKh[HT][NI][NS];
    __shared__ float  sXT[TT][NS];
    __shared__ double sA[NS][NS];
    __shared__ double sB[NS][NI];
    __shared__ double sP[NS][NS];
    __shared__ double sPA[NS][NS];
    __shared__ double sPB[NS][NI];
    __shared__ double sHs[NI][NS];
    __shared__ double sKt[NI][NS];
    __shared__ double sGi[NI][NI];
    __shared__ double sPp[NS][NS];
    __shared__ double sx[2][NS];
    __shared__ double su[NI];

    const int tid  = threadIdx.x;
    const int wid  = tid >> 6, lane = tid & 63;
    const int pi   = tid >> 3, pj0 = (tid & 7) * 4, pb0 = (tid & 7) * 2;
    const int ki   = tid >> 4, kj0 = (tid & 15) * 2;

    for (int idx = tid; idx < NS * NS; idx += 256) sA[idx >> 5][idx & 31] = (double)Ag[idx];
    for (int idx = tid; idx < NS * NI; idx += 256) sB[idx >> 4][idx & 15] = (double)Bg[idx];
    __syncthreads();

    auto step = [&](int t, bool storeK, int kbase, bool emitMu) {
        const float* Ct = Cg + t * NA * NA;
        {
            double a0 = 0, a1 = 0, a2 = 0, a3 = 0, b0 = 0, b1 = 0;
            for (int k = 0; k < NS; ++k) {
                const double p = sP[pi][k];
                a0 += p * sA[k][pj0 + 0]; a1 += p * sA[k][pj0 + 1];
                a2 += p * sA[k][pj0 + 2]; a3 += p * sA[k][pj0 + 3];
                b0 += p * sB[k][pb0 + 0]; b1 += p * sB[k][pb0 + 1];
            }
            sPA[pi][pj0 + 0] = a0; sPA[pi][pj0 + 1] = a1;
            sPA[pi][pj0 + 2] = a2; sPA[pi][pj0 + 3] = a3;
            sPB[pi][pb0 + 0] = b0; sPB[pi][pb0 + 1] = b1;
        }
        __syncthreads();
        if (wid == 0) {
            const int ri = lane & 15, cg = lane >> 4, jb = cg * 4;
            double g0 = (double)Ct[(NS + ri) * NA + NS + jb + 0];
            double g1 = (double)Ct[(NS + ri) * NA + NS + jb + 1];
            double g2 = (double)Ct[(NS + ri) * NA + NS + jb + 2];
            double g3 = (double)Ct[(NS + ri) * NA + NS + jb + 3];
            for (int k = 0; k < NS; ++k) {
                const double b = sB[k][ri];
                g0 += b * sPB[k][jb + 0]; g1 += b * sPB[k][jb + 1];
                g2 += b * sPB[k][jb + 2]; g3 += b * sPB[k][jb + 3];
            }
#pragma unroll
            for (int k = 0; k < NI; ++k) {
                const double myslot = ((k & 3) == 0) ? g0 : ((k & 3) == 1) ? g1
                                     : ((k & 3) == 2) ? g2 : g3;
                const int    plv  = k + ((k >> 2) << 4);
                const double piv  = __shfl(myslot, plv, 64);
                const double cv   = __shfl(myslot, ri + ((k >> 2) << 4), 64);
                const double pr0  = __shfl(g0, k + (cg << 4), 64);
                const double pr1  = __shfl(g1, k + (cg << 4), 64);
                const double pr2  = __shfl(g2, k + (cg << 4), 64);
                const double pr3  = __shfl(g3, k + (cg << 4), 64);
                const double ip   = 1.0 / piv;
                const bool   rk   = (ri == k);
                g0 = rk ? ((jb + 0 == k) ? ip : pr0 * ip)
                        : ((jb + 0 == k) ? -cv * ip : g0 - cv * pr0 * ip);
                g1 = rk ? ((jb + 1 == k) ? ip : pr1 * ip)
                        : ((jb + 1 == k) ? -cv * ip : g1 - cv * pr1 * ip);
                g2 = rk ? ((jb + 2 == k) ? ip : pr2 * ip)
                        : ((jb + 2 == k) ? -cv * ip : g2 - cv * pr2 * ip);
                g3 = rk ? ((jb + 3 == k) ? ip : pr3 * ip)
                        : ((jb + 3 == k) ? -cv * ip : g3 - cv * pr3 * ip);
            }
            sGi[ri][jb + 0] = g0; sGi[ri][jb + 1] = g1;
            sGi[ri][jb + 2] = g2; sGi[ri][jb + 3] = g3;
        } else {
            const int e0 = tid - 64;
            for (int e = e0; e < NI * NS; e += 192) {
                const int i = e >> 5, j = e & 31;
                double acc = (double)Ct[j * NA + NS + i];
                for (int k = 0; k < NS; ++k) acc += sB[k][i] * sPA[k][j];
                sHs[i][j] = acc;
            }
            for (int e = e0; e < NS * NS; e += 192) {
                const int i = e >> 5, j = e & 31;
                double acc = (double)Ct[i * NA + j];
                for (int k = 0; k < NS; ++k) acc += sA[k][i] * sPA[k][j];
                sPp[i][j] = acc;
            }
        }
        __syncthreads();
        {
            double a0 = 0, a1 = 0;
            for (int k = 0; k < NI; ++k) {
                const double g = sGi[ki][k];
                a0 += g * sHs[k][kj0 + 0];
                a1 += g * sHs[k][kj0 + 1];
            }
            sKt[ki][kj0 + 0] = a0; sKt[ki][kj0 + 1] = a1;
            if (storeK) {
                sKh[t - kbase][ki][kj0 + 0] = (float)a0;
                sKh[t - kbase][ki][kj0 + 1] = (float)a1;
            }
        }
        __syncthreads();
        {
            double a0 = sPp[pi][pj0 + 0], a1 = sPp[pi][pj0 + 1];
            double a2 = sPp[pi][pj0 + 2], a3 = sPp[pi][pj0 + 3];
            for (int k = 0; k < NI; ++k) {
                const double h = sHs[k][pi];
                a0 -= h * sKt[k][pj0 + 0]; a1 -= h * sKt[k][pj0 + 1];
                a2 -= h * sKt[k][pj0 + 2]; a3 -= h * sKt[k][pj0 + 3];
            }
            double b0 = sPp[pj0 + 0][pi], b1 = sPp[pj0 + 1][pi];
            double b2 = sPp[pj0 + 2][pi], b3 = sPp[pj0 + 3][pi];
            for (int k = 0; k < NI; ++k) {
                const double hk = sKt[k][pi];
                b0 -= sHs[k][pj0 + 0] * hk; b1 -= sHs[k][pj0 + 1] * hk;
                b2 -= sHs[k][pj0 + 2] * hk; b3 -= sHs[k][pj0 + 3] * hk;
            }
            sP[pi][pj0 + 0] = 0.5 * (a0 + b0); sP[pi][pj0 + 1] = 0.5 * (a1 + b1);
            sP[pi][pj0 + 2] = 0.5 * (a2 + b2); sP[pi][pj0 + 3] = 0.5 * (a3 + b3);
        }
        __syncthreads();
        if (emitMu && tid < NS) {
            double acc = 0.0;
            for (int k = 0; k < NS; ++k) acc += sP[tid][k] * (double)sXT[t][k];
            if (t == 0) acc = -acc;
            out[NA * TT + t * NS + tid] = (float)acc;
        }
    };

    auto sweep = [&](int tlo, int klo, int khi, bool emitMu) {
        for (int idx = tid; idx < NS * NS; idx += 256) sP[idx >> 5][idx & 31] = 0.0;
        __syncthreads();
        for (int t = TT - 1; t >= tlo; --t)
            step(t, (t >= klo && t < khi), klo, emitMu);
    };

    int cur = 0;
    auto forward = [&](int t0, int t1, int kbase) {
        for (int t = t0; t < t1; ++t) {
            if (tid < NS) {
                const float xv = (float)sx[cur][tid];
                sXT[t][tid] = xv;
                out[t * NA + tid] = xv;
            } else if (tid >= 64 && tid < 64 + NI) {
                const int i = tid - 64;
                double acc = 0.0;
                for (int k = 0; k < NS; ++k)
                    acc += (double)sKh[t - kbase][i][k] * sx[cur][k];
                su[i] = -acc;
                out[t * NA + NS + i] = (float)(-acc);
            }
            __syncthreads();
            if (t < TT - 1) {
                if (tid < NS) {
                    double acc = 0.0;
                    for (int k = 0; k < NS; ++k) acc += sA[tid][k] * sx[cur][k];
                    for (int k = 0; k < NI; ++k) acc += sB[tid][k] * su[k];
                    sx[cur ^ 1][tid] = acc;
                }
                __syncthreads();
                cur ^= 1;
            }
        }
    };

    sweep(0, 0, HT, false);
    if (tid < NS) sx[0][tid] = (double)x0g[tid];
    __syncthreads();
    forward(0, HT, 0);
    sweep(HT, HT, TT, false);
    forward(HT, TT, HT);
    sweep(0, 0, 0, true);
}

extern "C" void kernel_launch(void* const* d_in, const int* in_sizes, int n_in,
                              void* d_out, int out_size, void* d_ws, size_t ws_size,
                              hipStream_t stream) {
    // Bind by element count (A=1024, B=512, C=147456, x0=32), fallback dict order.
    const float *A = nullptr, *B = nullptr, *C = nullptr, *x0 = nullptr;
    for (int i = 0; i < n_in; ++i) {
        switch (in_sizes[i]) {
            case 1024:   A  = (const float*)d_in[i]; break;
            case 512:    B  = (const float*)d_in[i]; break;
            case 147456: C  = (const float*)d_in[i]; break;
            case 32:     x0 = (const float*)d_in[i]; break;
            default: break;
        }
    }
    if (!A || !B || !C || !x0) {
        A  = (const float*)d_in[0];
        B  = (const float*)d_in[1];
        C  = (const float*)d_in[2];
        x0 = (const float*)d_in[5];
    }

    const size_t need = (size_t)(TT * NI * NS + TT * NS * NS) * sizeof(float); // 384 KB
    if (d_ws != nullptr && ws_size >= need) {
        float* Kall = (float*)d_ws;
        float* Pall = Kall + TT * NI * NS;
        lqr_fast<<<1, 256, 0, stream>>>(A, B, C, x0, (float*)d_out, Kall, Pall);
    } else {
        lqr_kernel_fb<<<1, 256, 0, stream>>>(A, B, C, x0, (float*)d_out);
    }
}

// Round 17
// 543.563 us; speedup vs baseline: 1.5141x; 1.0380x over previous
//
#include <hip/hip_runtime.h>

#define NS 32   // n_state
#define NI 16   // n_input
#define NA 48   // n_all
#define TT 64   // horizon
#define HT 32   // half horizon
#define CSZ (NA * NA)      // 2304 floats per C_t
#define NTRI 528           // upper-triangle pairs of 32x32

// ---------------- FAST PATH ----------------
// r16 base (best: 564 us) + ONE structural change: symmetric-by-construction
// P update via upper-triangle enumeration (write (i,j) and (j,i) from one
// computed value). Cuts Pp dots 1024->528 and P-update dots 2048->528.
// Exact symmetry preserved (the r10-proven requirement; asymmetric recursion
// diverges — 126976 signature). f64 state/intermediates, f32 A/B in LDS
// (exact input promotion), exact-rcp shfl GJ in wave 0, 4 barriers/step,
// K_t/P_t f32 to d_ws, barrier forward rollout, parallel mu pass, f32 out.
__launch_bounds__(256, 1)
__global__ void lqr_fast(const float* __restrict__ Ag,
                         const float* __restrict__ Bg,
                         const float* __restrict__ Cg,
                         const float* __restrict__ x0g,
                         float* __restrict__ out,
                         float* __restrict__ Kall,   // [TT][NI][NS] f32
                         float* __restrict__ Pall)   // [TT][NS][NS] f32
{
    __shared__ float  sXT[TT][NS];      //  8192 B  x trajectory (f32)
    __shared__ float  sA[NS][33];       //  4224 B  A as f32 (exact input data)
    __shared__ float  sB[NS][17];       //  2176 B  B as f32 (exact input data)
    __shared__ double sP[NS][33];       //  8448 B  Riccati state (f64)
    __shared__ double sPA[NS][33];      //  8448 B  P*A
    __shared__ double sPB[NS][17];      //  4352 B  P*B
    __shared__ double sHs[NI][33];      //  4224 B  S^T + B^T P A
    __shared__ double sKt[NI][33];      //  4224 B  K_t (f64)
    __shared__ double sGi[NI][17];      //  2176 B  G^{-1}
    __shared__ double sPp[NS][33];      //  8448 B  Q + A^T P A (symmetric)
    __shared__ short  sTri[NTRI];       //  1056 B  packed (i<<8)|j, i<=j
    __shared__ double sx[2][NS];        //   512 B
    __shared__ double su[NI];           //   128 B   (~56 KB)

    const int tid  = threadIdx.x;
    const int wid  = tid >> 6, lane = tid & 63;
    const int pi   = tid >> 3, pj0 = (tid & 7) * 4, pb0 = (tid & 7) * 2;
    const int ki   = tid >> 4, kj0 = (tid & 15) * 2;

    for (int idx = tid; idx < NS * NS; idx += 256) {
        sA[idx >> 5][idx & 31] = Ag[idx];
        sP[idx >> 5][idx & 31] = 0.0;
    }
    for (int idx = tid; idx < NS * NI; idx += 256)
        sB[idx >> 4][idx & 15] = Bg[idx];
    // build upper-triangle (i,j) table once
    for (int e = tid; e < NTRI; e += 256) {
        int i = 0, rem = e;
        while (rem >= NS - i) { rem -= NS - i; ++i; }
        sTri[e] = (short)((i << 8) | (i + rem));
    }
    __syncthreads();

    // ---- backward sweep: 64 steps, 4 barriers each ----
    for (int t = TT - 1; t >= 0; --t) {
        const float* Ct = Cg + t * CSZ;

        // phase 1: PA = P*A (4 cols), PB = P*B (2 cols) per thread
        {
            double a0 = 0, a1 = 0, a2 = 0, a3 = 0, b0 = 0, b1 = 0;
            for (int k = 0; k < NS; ++k) {
                const double p = sP[pi][k];
                a0 += p * (double)sA[k][pj0 + 0]; a1 += p * (double)sA[k][pj0 + 1];
                a2 += p * (double)sA[k][pj0 + 2]; a3 += p * (double)sA[k][pj0 + 3];
                b0 += p * (double)sB[k][pb0 + 0]; b1 += p * (double)sB[k][pb0 + 1];
            }
            sPA[pi][pj0 + 0] = a0; sPA[pi][pj0 + 1] = a1;
            sPA[pi][pj0 + 2] = a2; sPA[pi][pj0 + 3] = a3;
            sPB[pi][pb0 + 0] = b0; sPB[pi][pb0 + 1] = b1;
        }
        __syncthreads();                                   // barrier A

        // phase 2 (overlapped): wave0 -> G^{-1} (register GJ via __shfl);
        //   waves 1-3 -> Hs (full 16x32) + Pp (upper triangle, write both)
        if (wid == 0) {
            const int ri = lane & 15, cg = lane >> 4, jb = cg * 4;
            double g0 = (double)Ct[(NS + ri) * NA + NS + jb + 0];
            double g1 = (double)Ct[(NS + ri) * NA + NS + jb + 1];
            double g2 = (double)Ct[(NS + ri) * NA + NS + jb + 2];
            double g3 = (double)Ct[(NS + ri) * NA + NS + jb + 3];
            for (int k = 0; k < NS; ++k) {
                const double b = (double)sB[k][ri];
                g0 += b * sPB[k][jb + 0]; g1 += b * sPB[k][jb + 1];
                g2 += b * sPB[k][jb + 2]; g3 += b * sPB[k][jb + 3];
            }
#pragma unroll
            for (int k = 0; k < NI; ++k) {
                const double myslot = ((k & 3) == 0) ? g0 : ((k & 3) == 1) ? g1
                                     : ((k & 3) == 2) ? g2 : g3;
                const int    plv  = k + ((k >> 2) << 4);      // lane of (k,k)
                const double piv  = __shfl(myslot, plv, 64);
                const double cv   = __shfl(myslot, ri + ((k >> 2) << 4), 64); // (ri,k)
                const double pr0  = __shfl(g0, k + (cg << 4), 64);            // (k,jb+j)
                const double pr1  = __shfl(g1, k + (cg << 4), 64);
                const double pr2  = __shfl(g2, k + (cg << 4), 64);
                const double pr3  = __shfl(g3, k + (cg << 4), 64);
                const double ip   = 1.0 / piv;
                const bool   rk   = (ri == k);
                g0 = rk ? ((jb + 0 == k) ? ip : pr0 * ip)
                        : ((jb + 0 == k) ? -cv * ip : g0 - cv * pr0 * ip);
                g1 = rk ? ((jb + 1 == k) ? ip : pr1 * ip)
                        : ((jb + 1 == k) ? -cv * ip : g1 - cv * pr1 * ip);
                g2 = rk ? ((jb + 2 == k) ? ip : pr2 * ip)
                        : ((jb + 2 == k) ? -cv * ip : g2 - cv * pr2 * ip);
                g3 = rk ? ((jb + 3 == k) ? ip : pr3 * ip)
                        : ((jb + 3 == k) ? -cv * ip : g3 - cv * pr3 * ip);
            }
            sGi[ri][jb + 0] = g0; sGi[ri][jb + 1] = g1;
            sGi[ri][jb + 2] = g2; sGi[ri][jb + 3] = g3;
        } else {
            const int e0 = tid - 64;
            for (int e = e0; e < NI * NS; e += 192) {
                const int i = e >> 5, j = e & 31;
                double acc = (double)Ct[j * NA + NS + i];
                for (int k = 0; k < NS; ++k) acc += (double)sB[k][i] * sPA[k][j];
                sHs[i][j] = acc;
            }
            for (int e = e0; e < NTRI; e += 192) {
                const int p = sTri[e];
                const int i = p >> 8, j = p & 255;
                double acc = (double)Ct[i * NA + j];
                for (int k = 0; k < NS; ++k) acc += (double)sA[k][i] * sPA[k][j];
                sPp[i][j] = acc;
                sPp[j][i] = acc;       // symmetric by construction
            }
        }
        __syncthreads();                                   // barrier B

        // phase 3: K = G^{-1} Hs (2 cols per thread); f32 K to d_ws
        {
            double a0 = 0, a1 = 0;
            for (int k = 0; k < NI; ++k) {
                const double g = sGi[ki][k];
                a0 += g * sHs[k][kj0 + 0];
                a1 += g * sHs[k][kj0 + 1];
            }
            sKt[ki][kj0 + 0] = a0; sKt[ki][kj0 + 1] = a1;
            Kall[t * NI * NS + ki * NS + kj0 + 0] = (float)a0;
            Kall[t * NI * NS + ki * NS + kj0 + 1] = (float)a1;
        }
        __syncthreads();                                   // barrier C

        // phase 4: P = Pp - Hs^T K on the upper triangle, write both slots
        // (exact symmetry by construction — load-bearing for stability)
        for (int e = tid; e < NTRI; e += 256) {
            const int p = sTri[e];
            const int i = p >> 8, j = p & 255;
            double a = sPp[i][j];
            for (int k = 0; k < NI; ++k) a -= sHs[k][i] * sKt[k][j];
            sP[i][j] = a;
            sP[j][i] = a;
            const float af = (float)a;
            Pall[t * NS * NS + i * NS + j] = af;
            Pall[t * NS * NS + j * NS + i] = af;
        }
        __syncthreads();                                   // barrier D
    }

    // ---- forward rollout: tau (x + u), record x trajectory ----
    if (tid < NS) sx[0][tid] = (double)x0g[tid];
    __syncthreads();
    int cur = 0;
    for (int t = 0; t < TT; ++t) {
        if (tid < NS) {
            const float xv = (float)sx[cur][tid];
            sXT[t][tid] = xv;
            out[t * NA + tid] = xv;
        } else if (tid >= 64 && tid < 64 + NI) {
            const int i = tid - 64;
            const float* Kt = Kall + t * NI * NS + i * NS;
            double acc = 0.0;
            for (int k = 0; k < NS; ++k) acc += (double)Kt[k] * sx[cur][k];
            su[i] = -acc;
            out[t * NA + NS + i] = (float)(-acc);
        }
        __syncthreads();
        if (t < TT - 1) {
            if (tid < NS) {
                double acc = 0.0;
                for (int k = 0; k < NS; ++k) acc += (double)sA[tid][k] * sx[cur][k];
                for (int k = 0; k < NI; ++k) acc += (double)sB[tid][k] * su[k];
                sx[cur ^ 1][tid] = acc;
            }
            __syncthreads();
            cur ^= 1;
        }
    }
    __syncthreads();

    // ---- mu pass: mu_t = P_t x_t (2048 parallel dots); mu_0 negated ----
    for (int e = tid; e < TT * NS; e += 256) {
        const int t = e >> 5, i = e & 31;
        const float* Pt = Pall + t * NS * NS + i * NS;
        double acc = 0.0;
        for (int k = 0; k < NS; ++k) acc += (double)Pt[k] * (double)sXT[t][k];
        if (t == 0) acc = -acc;
        out[NA * TT + t * NS + i] = (float)acc;
    }
}

// ---------------- FALLBACK (round-11/12, passing) — if ws_size < 384 KB ----
__launch_bounds__(256, 1)
__global__ void lqr_kernel_fb(const float* __restrict__ Ag,
                              const float* __restrict__ Bg,
                              const float* __restrict__ Cg,
                              const float* __restrict__ x0g,
                              float* __restrict__ out)
{
    __shared__ float  sKh[HT][NI][NS];
    __shared__ float  sXT[TT][NS];
    __shared__ double sA[NS][NS];
    __shared__ double sB[NS][NI];
    __shared__ double sP[NS][NS];
    __shared__ double sPA[NS][NS];
    __shared__ double sPB[NS][NI];
    __shared__ double sHs[NI][NS];
    __shared__ double sKt[NI][NS];
    __shared__ double sGi[NI][NI];
    __shared__ double sPp[NS][NS];
    __shared__ double sx[2][NS];
    __shared__ double su[NI];

    const int tid  = threadIdx.x;
    const int wid  = tid >> 6, lane = tid & 63;
    const int pi   = tid >> 3, pj0 = (tid & 7) * 4, pb0 = (tid & 7) * 2;
    const int ki   = tid >> 4, kj0 = (tid & 15) * 2;

    for (int idx = tid; idx < NS * NS; idx += 256) sA[idx >> 5][idx & 31] = (double)Ag[idx];
    for (int idx = tid; idx < NS * NI; idx += 256) sB[idx >> 4][idx & 15] = (double)Bg[idx];
    __syncthreads();

    auto step = [&](int t, bool storeK, int kbase, bool emitMu) {
        const float* Ct = Cg + t * NA * NA;
        {
            double a0 = 0, a1 = 0, a2 = 0, a3 = 0, b0 = 0, b1 = 0;
            for (int k = 0; k < NS; ++k) {
                const double p = sP[pi][k];
                a0 += p * sA[k][pj0 + 0]; a1 += p * sA[k][pj0 + 1];
                a2 += p * sA[k][pj0 + 2]; a3 += p * sA[k][pj0 + 3];
                b0 += p * sB[k][pb0 + 0]; b1 += p * sB[k][pb0 + 1];
            }
            sPA[pi][pj0 + 0] = a0; sPA[pi][pj0 + 1] = a1;
            sPA[pi][pj0 + 2] = a2; sPA[pi][pj0 + 3] = a3;
            sPB[pi][pb0 + 0] = b0; sPB[pi][pb0 + 1] = b1;
        }
        __syncthreads();
        if (wid == 0) {
            const int ri = lane & 15, cg = lane >> 4, jb = cg * 4;
            double g0 = (double)Ct[(NS + ri) * NA + NS + jb + 0];
            double g1 = (double)Ct[(NS + ri) * NA + NS + jb + 1];
            double g2 = (double)Ct[(NS + ri) * NA + NS + jb + 2];
            double g3 = (double)Ct[(NS + ri) * NA + NS + jb + 3];
            for (int k = 0; k < NS; ++k) {
                const double b = sB[k][ri];
                g0 += b * sPB[k][jb + 0]; g1 += b * sPB[k][jb + 1];
                g2 += b * sPB[k][jb + 2]; g3 += b * sPB[k][jb + 3];
            }
#pragma unroll
            for (int k = 0; k < NI; ++k) {
                const double myslot = ((k & 3) == 0) ? g0 : ((k & 3) == 1) ? g1
                                     : ((k & 3) == 2) ? g2 : g3;
                const int    plv  = k + ((k >> 2) << 4);
                const double piv  = __shfl(myslot, plv, 64);
                const double cv   = __shfl(myslot, ri + ((k >> 2) << 4), 64);
                const double pr0  = __shfl(g0, k + (cg << 4), 64);
                const double pr1  = __shfl(g1, k + (cg << 4), 64);
                const double pr2  = __shfl(g2, k + (cg << 4), 64);
                const double pr3  = __shfl(g3, k + (cg << 4), 64);
                const double ip   = 1.0 / piv;
                const bool   rk   = (ri == k);
                g0 = rk ? ((jb + 0 == k) ? ip : pr0 * ip)
                        : ((jb + 0 == k) ? -cv * ip : g0 - cv * pr0 * ip);
                g1 = rk ? ((jb + 1 == k) ? ip : pr1 * ip)
                        : ((jb + 1 == k) ? -cv * ip : g1 - cv * pr1 * ip);
                g2 = rk ? ((jb + 2 == k) ? ip : pr2 * ip)
                        : ((jb + 2 == k) ? -cv * ip : g2 - cv * pr2 * ip);
                g3 = rk ? ((jb + 3 == k) ? ip : pr3 * ip)
                        : ((jb + 3 == k) ? -cv * ip : g3 - cv * pr3 * ip);
            }
            sGi[ri][jb + 0] = g0; sGi[ri][jb + 1] = g1;
            sGi[ri][jb + 2] = g2; sGi[ri][jb + 3] = g3;
        } else {
            const int e0 = tid - 64;
            for (int e = e0; e < NI * NS; e += 192) {
                const int i = e >> 5, j = e & 31;
                double acc = (double)Ct[j * NA + NS + i];
                for (int k = 0; k < NS; ++k) acc += sB[k][i] * sPA[k][j];
                sHs[i][j] = acc;
            }
            for (int e = e0; e < NS * NS; e += 192) {
                const int i = e >> 5, j = e & 31;
                double acc = (double)Ct[i * NA + j];
                for (int k = 0; k < NS; ++k) acc += sA[k][i] * sPA[k][j];
                sPp[i][j] = acc;
            }
        }
        __syncthreads();
        {
            double a0 = 0, a1 = 0;
            for (int k = 0; k < NI; ++k) {
                const double g = sGi[ki][k];
                a0 += g * sHs[k][kj0 + 0];
                a1 += g * sHs[k][kj0 + 1];
            }
            sKt[ki][kj0 + 0] = a0; sKt[ki][kj0 + 1] = a1;
            if (storeK) {
                sKh[t - kbase][ki][kj0 + 0] = (float)a0;
                sKh[t - kbase][ki][kj0 + 1] = (float)a1;
            }
        }
        __syncthreads();
        {
            double a0 = sPp[pi][pj0 + 0], a1 = sPp[pi][pj0 + 1];
            double a2 = sPp[pi][pj0 + 2], a3 = sPp[pi][pj0 + 3];
            for (int k = 0; k < NI; ++k) {
                const double h = sHs[k][pi];
                a0 -= h * sKt[k][pj0 + 0]; a1 -= h * sKt[k][pj0 + 1];
                a2 -= h * sKt[k][pj0 + 2]; a3 -= h * sKt[k][pj0 + 3];
            }
            double b0 = sPp[pj0 + 0][pi], b1 = sPp[pj0 + 1][pi];
            double b2 = sPp[pj0 + 2][pi], b3 = sPp[pj0 + 3][pi];
            for (int k = 0; k < NI; ++k) {
                const double hk = sKt[k][pi];
                b0 -= sHs[k][pj0 + 0] * hk; b1 -= sHs[k][pj0 + 1] * hk;
                b2 -= sHs[k][pj0 + 2] * hk; b3 -= sHs[k][pj0 + 3] * hk;
            }
            sP[pi][pj0 + 0] = 0.5 * (a0 + b0); sP[pi][pj0 + 1] = 0.5 * (a1 + b1);
            sP[pi][pj0 + 2] = 0.5 * (a2 + b2); sP[pi][pj0 + 3] = 0.5 * (a3 + b3);
        }
        __syncthreads();
        if (emitMu && tid < NS) {
            double acc = 0.0;
            for (int k = 0; k < NS; ++k) acc += sP[tid][k] * (double)sXT[t][k];
            if (t == 0) acc = -acc;
            out[NA * TT + t * NS + tid] = (float)acc;
        }
    };

    auto sweep = [&](int tlo, int klo, int khi, bool emitMu) {
        for (int idx = tid; idx < NS * NS; idx += 256) sP[idx >> 5][idx & 31] = 0.0;
        __syncthreads();
        for (int t = TT - 1; t >= tlo; --t)
            step(t, (t >= klo && t < khi), klo, emitMu);
    };

    int cur = 0;
    auto forward = [&](int t0, int t1, int kbase) {
        for (int t = t0; t < t1; ++t) {
            if (tid < NS) {
                const float xv = (float)sx[cur][tid];
                sXT[t][tid] = xv;
                out[t * NA + tid] = xv;
            } else if (tid >= 64 && tid < 64 + NI) {
                const int i = tid - 64;
                double acc = 0.0;
                for (int k = 0; k < NS; ++k)
                    acc += (double)sKh[t - kbase][i][k] * sx[cur][k];
                su[i] = -acc;
                out[t * NA + NS + i] = (float)(-acc);
            }
            __syncthreads();
            if (t < TT - 1) {
                if (tid < NS) {
                    double acc = 0.0;
                    for (int k = 0; k < NS; ++k) acc += sA[tid][k] * sx[cur][k];
                    for (int k = 0; k < NI; ++k) acc += sB[tid][k] * su[k];
                    sx[cur ^ 1][tid] = acc;
                }
                __syncthreads();
                cur ^= 1;
            }
        }
    };

    sweep(0, 0, HT, false);
    if (tid < NS) sx[0][tid] = (double)x0g[tid];
    __syncthreads();
    forward(0, HT, 0);
    sweep(HT, HT, TT, false);
    forward(HT, TT, HT);
    sweep(0, 0, 0, true);
}

extern "C" void kernel_launch(void* const* d_in, const int* in_sizes, int n_in,
                              void* d_out, int out_size, void* d_ws, size_t ws_size,
                              hipStream_t stream) {
    // Bind by element count (A=1024, B=512, C=147456, x0=32), fallback dict order.
    const float *A = nullptr, *B = nullptr, *C = nullptr, *x0 = nullptr;
    for (int i = 0; i < n_in; ++i) {
        switch (in_sizes[i]) {
            case 1024:   A  = (const float*)d_in[i]; break;
            case 512:    B  = (const float*)d_in[i]; break;
            case 147456: C  = (const float*)d_in[i]; break;
            case 32:     x0 = (const float*)d_in[i]; break;
            default: break;
        }
    }
    if (!A || !B || !C || !x0) {
        A  = (const float*)d_in[0];
        B  = (const float*)d_in[1];
        C  = (const float*)d_in[2];
        x0 = (const float*)d_in[5];
    }

    const size_t need = (size_t)(TT * NI * NS + TT * NS * NS) * sizeof(float); // 384 KB
    if (d_ws != nullptr && ws_size >= need) {
        float* Kall = (float*)d_ws;
        float* Pall = Kall + TT * NI * NS;
        lqr_fast<<<1, 256, 0, stream>>>(A, B, C, x0, (float*)d_out, Kall, Pall);
    } else {
        lqr_kernel_fb<<<1, 256, 0, stream>>>(A, B, C, x0, (float*)d_out);
    }
}